// Round 1
// baseline (2078.730 us; speedup 1.0000x reference)
//
#include <hip/hip_runtime.h>

#define SEQ 2048
#define NB 4
#define DIN 768
#define EDIM 768
#define NH 12
#define HDIM 64
#define QKVN 2304
#define SCALE 0.125f
#define PADV -1e9f

#define TQ 16
#define NCMAX 432   // >= 2*205 + 16, 16B-aligned stride
#define TACC 27     // ceil(16*426/256)

typedef unsigned short ushort_t;

__device__ __forceinline__ float bf2f(ushort_t u) {
    union { unsigned int i; float f; } v; v.i = ((unsigned int)u) << 16; return v.f;
}
__device__ __forceinline__ ushort_t f2bf(float f) {
    union { float f; unsigned int i; } v; v.f = f;
    unsigned int r = (v.i + 0x7fffu + ((v.i >> 16) & 1u)) >> 16;
    return (ushort_t)r;
}
__device__ __forceinline__ void unpack2(unsigned int u, float& lo, float& hi) {
    union { unsigned int i; float f; } a, b;
    a.i = u << 16; b.i = u & 0xffff0000u;
    lo = a.f; hi = b.f;
}

// ---------------- per-batch window size ----------------
__global__ void wsz_kernel(const int* __restrict__ mask, int* __restrict__ wszp) {
    int b = blockIdx.x;
    __shared__ int cnt;
    if (threadIdx.x == 0) cnt = 0;
    __syncthreads();
    int local = 0;
    for (int s = threadIdx.x; s < SEQ; s += blockDim.x)
        local += (mask[b * SEQ + s] == 0) ? 1 : 0;
    for (int o = 32; o; o >>= 1) local += __shfl_down(local, o, 64);
    if ((threadIdx.x & 63) == 0) atomicAdd(&cnt, local);
    __syncthreads();
    if (threadIdx.x == 0) {
        int len = cnt; if (len > 2048) len = 2048;
        float w = ceilf(((float)len * 10.0f) / 100.0f);
        int wsz = (int)w;
        if (wsz < 2) wsz = 2;
        wszp[b] = wsz;
    }
}

// ---------------- fp32 tiled GEMM: C[M][N] = A[M][K] @ Bw[N][K]^T + bias ----------------
template<int OUT_BF16>
__global__ __launch_bounds__(256) void gemm_bias_kernel(
    const float* __restrict__ A, const float* __restrict__ Bw,
    const float* __restrict__ bias, void* __restrict__ Cout,
    int M, int N, int K)
{
    __shared__ float As[64][36];   // [m][k], stride 36 (16B aligned, bank-safe)
    __shared__ float Bs[32][65];   // [k][n], stride 65
    const int tid = threadIdx.x;
    const int bm = blockIdx.y * 64;
    const int bn = blockIdx.x * 64;
    const int tm = tid >> 4;      // 0..15
    const int tn = tid & 15;      // 0..15
    const int ra = tid >> 2;      // 0..63
    const int ka = (tid & 3) * 8; // 0,8,16,24
    float acc[4][4] = {};
    for (int k0 = 0; k0 < K; k0 += 32) {
        const float* srcA = A + (size_t)(bm + ra) * K + k0 + ka;
        float4 a0 = *(const float4*)srcA;
        float4 a1 = *(const float4*)(srcA + 4);
        *(float4*)&As[ra][ka]     = a0;
        *(float4*)&As[ra][ka + 4] = a1;
        const float* srcB = Bw + (size_t)(bn + ra) * K + k0 + ka;
        float4 b0 = *(const float4*)srcB;
        float4 b1 = *(const float4*)(srcB + 4);
        Bs[ka+0][ra] = b0.x; Bs[ka+1][ra] = b0.y; Bs[ka+2][ra] = b0.z; Bs[ka+3][ra] = b0.w;
        Bs[ka+4][ra] = b1.x; Bs[ka+5][ra] = b1.y; Bs[ka+6][ra] = b1.z; Bs[ka+7][ra] = b1.w;
        __syncthreads();
        #pragma unroll
        for (int kk = 0; kk < 32; ++kk) {
            float a[4], bb[4];
            #pragma unroll
            for (int r = 0; r < 4; ++r) a[r] = As[tm*4+r][kk];
            #pragma unroll
            for (int c = 0; c < 4; ++c) bb[c] = Bs[kk][tn*4+c];
            #pragma unroll
            for (int r = 0; r < 4; ++r)
                #pragma unroll
                for (int c = 0; c < 4; ++c)
                    acc[r][c] = fmaf(a[r], bb[c], acc[r][c]);
        }
        __syncthreads();
    }
    const int gn = bn + tn * 4;
    float bv[4] = { bias[gn], bias[gn+1], bias[gn+2], bias[gn+3] };
    #pragma unroll
    for (int r = 0; r < 4; ++r) {
        int gm = bm + tm * 4 + r;
        if (OUT_BF16) {
            ushort4 st;
            st.x = f2bf(acc[r][0] + bv[0]);
            st.y = f2bf(acc[r][1] + bv[1]);
            st.z = f2bf(acc[r][2] + bv[2]);
            st.w = f2bf(acc[r][3] + bv[3]);
            *(ushort4*)((ushort_t*)Cout + (size_t)gm * N + gn) = st;
        } else {
            float4 st;
            st.x = acc[r][0] + bv[0];
            st.y = acc[r][1] + bv[1];
            st.z = acc[r][2] + bv[2];
            st.w = acc[r][3] + bv[3];
            *(float4*)((float*)Cout + (size_t)gm * N + gn) = st;
        }
    }
}

// ---------------- fused windowed attention ----------------
// grid: (SEQ/TQ, NB); block handles q rows [iq0, iq0+16) for ALL heads.
__global__ __launch_bounds__(256) void attn_kernel(
    const ushort_t* __restrict__ qkv,   // [NB*SEQ][2304] bf16
    const float* __restrict__ mmask,    // [NB][SEQ][SEQ]
    const int* __restrict__ wszp,       // [NB]
    float* __restrict__ values,         // [NB*SEQ][768] f32
    float* __restrict__ attn_out)       // [NB][SEQ][SEQ]
{
    __shared__ float plog[TQ][NCMAX];   // logits -> exp values
    __shared__ float ks[64][65];        // k chunk [j][d]
    __shared__ float qs[TQ][68];        // q tile [i][d]
    __shared__ float invsum[TQ];
    const int tid  = threadIdx.x;
    const int b    = blockIdx.y;
    const int iq0  = blockIdx.x * TQ;
    const int wsz  = wszp[b];
    const int jlo  = max(0, iq0 - wsz);
    const int jhi  = min(SEQ - 1, iq0 + TQ - 1 + wsz);
    const int ncols = jhi - jlo + 1;
    const int irow = tid >> 4;   // 0..15
    const int c16  = tid & 15;   // 0..15
    float amean[TACC];
    #pragma unroll
    for (int t = 0; t < TACC; ++t) amean[t] = 0.f;

    for (int h = 0; h < NH; ++h) {
        const int hq = h * 192;
        // ---- stage Q tile ----
        {
            int r = tid >> 4, d0 = (tid & 15) * 4;
            const ushort_t* src = qkv + ((size_t)(b * SEQ + iq0 + r)) * QKVN + hq + d0;
            ushort4 u = *(const ushort4*)src;
            float4 f;
            f.x = bf2f(u.x); f.y = bf2f(u.y); f.z = bf2f(u.z); f.w = bf2f(u.w);
            *(float4*)&qs[r][d0] = f;
        }
        __syncthreads();
        // ---- logits in chunks of 64 columns ----
        for (int jc0 = 0; jc0 < ncols; jc0 += 64) {
            const int nj = min(64, ncols - jc0);
            {
                int r = tid >> 2, p = (tid & 3) * 16;
                if (r < nj) {
                    const ushort_t* src = qkv + ((size_t)(b * SEQ + jlo + jc0 + r)) * QKVN + hq + 64 + p;
                    uint4 u0 = *(const uint4*)src;
                    uint4 u1 = *(const uint4*)(src + 8);
                    unpack2(u0.x, ks[r][p+0], ks[r][p+1]);
                    unpack2(u0.y, ks[r][p+2], ks[r][p+3]);
                    unpack2(u0.z, ks[r][p+4], ks[r][p+5]);
                    unpack2(u0.w, ks[r][p+6], ks[r][p+7]);
                    unpack2(u1.x, ks[r][p+8], ks[r][p+9]);
                    unpack2(u1.y, ks[r][p+10], ks[r][p+11]);
                    unpack2(u1.z, ks[r][p+12], ks[r][p+13]);
                    unpack2(u1.w, ks[r][p+14], ks[r][p+15]);
                }
            }
            __syncthreads();
            {
                const int j0 = c16 * 4;
                float dot[4] = {0.f, 0.f, 0.f, 0.f};
                if (j0 < nj) {
                    #pragma unroll
                    for (int d = 0; d < 64; ++d) {
                        float a = qs[irow][d];
                        dot[0] = fmaf(a, ks[j0+0][d], dot[0]);
                        dot[1] = fmaf(a, ks[j0+1][d], dot[1]);
                        dot[2] = fmaf(a, ks[j0+2][d], dot[2]);
                        dot[3] = fmaf(a, ks[j0+3][d], dot[3]);
                    }
                }
                const int gi = iq0 + irow;
                #pragma unroll
                for (int c = 0; c < 4; ++c) {
                    int j = j0 + c;
                    if (j < nj) {
                        int gj = jlo + jc0 + j;
                        float mm = mmask[((size_t)b * SEQ + gi) * SEQ + gj];
                        int dist = gi > gj ? gi - gj : gj - gi;
                        float l = (dist > wsz || mm == PADV) ? PADV
                                                            : fmaf(dot[c], SCALE, mm);
                        plog[irow][jc0 + j] = l;
                    }
                }
            }
            __syncthreads();
        }
        // ---- softmax per row (16 threads per row) ----
        {
            float m = -3.4e38f;
            for (int j = c16; j < ncols; j += 16) m = fmaxf(m, plog[irow][j]);
            #pragma unroll
            for (int o = 8; o; o >>= 1) m = fmaxf(m, __shfl_xor(m, o, 16));
            float s = 0.f;
            for (int j = c16; j < ncols; j += 16) {
                float e = __expf(plog[irow][j] - m);
                plog[irow][j] = e;
                s += e;
            }
            #pragma unroll
            for (int o = 8; o; o >>= 1) s += __shfl_xor(s, o, 16);
            if (c16 == 0) invsum[irow] = 1.0f / s;
        }
        __syncthreads();
        // ---- accumulate head-mean of attn (registers) ----
        {
            const int tot = TQ * ncols;
            #pragma unroll
            for (int t = 0; t < TACC; ++t) {
                int e = tid + t * 256;
                if (e < tot) {
                    int i = e / ncols;
                    int j = e - i * ncols;
                    amean[t] += plog[i][j] * invsum[i];
                }
            }
        }
        // ---- PV: row irow, dims d = c16*4 .. +3 ----
        {
            float a0 = 0.f, a1 = 0.f, a2 = 0.f, a3 = 0.f;
            const ushort_t* vbase = qkv + ((size_t)(b * SEQ + jlo)) * QKVN + hq + 128 + c16 * 4;
            for (int j = 0; j < ncols; ++j) {
                float p = plog[irow][j];
                ushort4 u = *(const ushort4*)(vbase + (size_t)j * QKVN);
                a0 = fmaf(p, bf2f(u.x), a0);
                a1 = fmaf(p, bf2f(u.y), a1);
                a2 = fmaf(p, bf2f(u.z), a2);
                a3 = fmaf(p, bf2f(u.w), a3);
            }
            float is = invsum[irow];
            float* dst = values + ((size_t)(b * SEQ + iq0 + irow)) * EDIM + h * 64 + c16 * 4;
            float4 st; st.x = a0 * is; st.y = a1 * is; st.z = a2 * is; st.w = a3 * is;
            *(float4*)dst = st;
        }
        __syncthreads();   // protect plog/qs/invsum before next head
    }
    // ---- write attn mean (out-of-window already zeroed by memset) ----
    {
        const float invH = 1.0f / (float)NH;
        const int tot = TQ * ncols;
        float* ab = attn_out + ((size_t)b * SEQ + iq0) * SEQ + jlo;
        #pragma unroll
        for (int t = 0; t < TACC; ++t) {
            int e = tid + t * 256;
            if (e < tot) {
                int i = e / ncols;
                int j = e - i * ncols;
                ab[(size_t)i * SEQ + j] = amean[t] * invH;
            }
        }
    }
}

extern "C" void kernel_launch(void* const* d_in, const int* in_sizes, int n_in,
                              void* d_out, int out_size, void* d_ws, size_t ws_size,
                              hipStream_t stream) {
    const float* x      = (const float*)d_in[0];
    const int*   pad    = (const int*)d_in[1];
    const float* mmask  = (const float*)d_in[2];
    const float* qkv_w  = (const float*)d_in[3];
    const float* qkv_b  = (const float*)d_in[4];
    const float* o_w    = (const float*)d_in[5];
    const float* o_b    = (const float*)d_in[6];

    float* out_o    = (float*)d_out;
    float* out_attn = out_o + (size_t)NB * SEQ * EDIM;

    // workspace layout
    ushort_t* qkv    = (ushort_t*)d_ws;                              // NB*SEQ*2304 bf16
    float*    values = (float*)(qkv + (size_t)NB * SEQ * QKVN);      // NB*SEQ*768 f32
    int*      wszp   = (int*)(values + (size_t)NB * SEQ * EDIM);     // NB ints

    // zero the attn_mean region (out-of-window entries must be exactly 0)
    hipMemsetAsync(out_attn, 0, (size_t)NB * SEQ * SEQ * sizeof(float), stream);

    wsz_kernel<<<NB, 256, 0, stream>>>(pad, wszp);

    // qkv = x @ qkv_w^T + qkv_b  (M=8192, N=2304, K=768), bf16 out
    gemm_bias_kernel<1><<<dim3(QKVN / 64, (NB * SEQ) / 64), 256, 0, stream>>>(
        x, qkv_w, qkv_b, (void*)qkv, NB * SEQ, QKVN, DIN);

    // fused windowed attention
    attn_kernel<<<dim3(SEQ / TQ, NB), 256, 0, stream>>>(
        qkv, mmask, wszp, values, out_attn);

    // o = values @ o_w^T + o_b  (M=8192, N=768, K=768), f32 out
    gemm_bias_kernel<0><<<dim3(EDIM / 64, (NB * SEQ) / 64), 256, 0, stream>>>(
        values, o_w, o_b, (void*)out_o, NB * SEQ, EDIM, EDIM);
}

// Round 2
// 780.819 us; speedup vs baseline: 2.6622x; 2.6622x over previous
//
#include <hip/hip_runtime.h>

#define SEQ 2048
#define NB 4
#define DIN 768
#define EDIM 768
#define NH 12
#define HDIM 64
#define QKVN 2304
#define SCALE 0.125f
#define PADV -1e9f

#define TQ 16
#define NCMAX 432   // >= 2*205 + 16

typedef unsigned short ushort_t;
typedef __attribute__((ext_vector_type(8))) short bf16x8;
typedef __attribute__((ext_vector_type(4))) float f32x4;

__device__ __forceinline__ float bf2f(ushort_t u) {
    union { unsigned int i; float f; } v; v.i = ((unsigned int)u) << 16; return v.f;
}
__device__ __forceinline__ ushort_t f2bf(float f) {
    union { float f; unsigned int i; } v; v.f = f;
    unsigned int r = (v.i + 0x7fffu + ((v.i >> 16) & 1u)) >> 16;
    return (ushort_t)r;
}
__device__ __forceinline__ void unpack2(unsigned int u, float& lo, float& hi) {
    union { unsigned int i; float f; } a, b;
    a.i = u << 16; b.i = u & 0xffff0000u;
    lo = a.f; hi = b.f;
}

// ---------------- per-batch window size ----------------
__global__ void wsz_kernel(const int* __restrict__ mask, int* __restrict__ wszp) {
    int b = blockIdx.x;
    __shared__ int cnt;
    if (threadIdx.x == 0) cnt = 0;
    __syncthreads();
    int local = 0;
    for (int s = threadIdx.x; s < SEQ; s += blockDim.x)
        local += (mask[b * SEQ + s] == 0) ? 1 : 0;
    for (int o = 32; o; o >>= 1) local += __shfl_down(local, o, 64);
    if ((threadIdx.x & 63) == 0) atomicAdd(&cnt, local);
    __syncthreads();
    if (threadIdx.x == 0) {
        int len = cnt; if (len > 2048) len = 2048;
        float w = ceilf(((float)len * 10.0f) / 100.0f);
        int wsz = (int)w;
        if (wsz < 2) wsz = 2;
        wszp[b] = wsz;
    }
}

// ---------------- fp32 -> bf16 conversion ----------------
__global__ void cvt_kernel(const float* __restrict__ in, ushort_t* __restrict__ out, int n4) {
    int i = blockIdx.x * blockDim.x + threadIdx.x;
    if (i < n4) {
        float4 f = ((const float4*)in)[i];
        ushort4 u;
        u.x = f2bf(f.x); u.y = f2bf(f.y); u.z = f2bf(f.z); u.w = f2bf(f.w);
        ((ushort4*)out)[i] = u;
    }
}

// ---------------- bf16 MFMA GEMM: C[M][N] = A[M][K] @ Bt[N][K]^T + bias ----------------
// 64x64 tile, BK=64, 256 threads = 4 waves; wave w -> rows [w*16,w*16+16), 4 col-tiles.
template<int OUT_BF16>
__global__ __launch_bounds__(256) void mfma_gemm_kernel(
    const ushort_t* __restrict__ A, const ushort_t* __restrict__ Bt,
    const float* __restrict__ bias, void* __restrict__ Cout,
    int M, int N, int K)
{
    __shared__ __align__(16) ushort_t als[64 * 72];   // row stride 72 elems (144B)
    __shared__ __align__(16) ushort_t bls[64 * 72];
    const int tid  = threadIdx.x;
    const int bm   = blockIdx.y * 64;
    const int bn   = blockIdx.x * 64;
    const int w    = tid >> 6;
    const int l    = tid & 63;
    const int quad = l >> 4;
    const int lr   = l & 15;
    const int srow = tid >> 2;        // 0..63
    const int scol = (tid & 3) * 8;   // 0,8,16,24 (elems)

    f32x4 acc[4];
    #pragma unroll
    for (int c = 0; c < 4; ++c)
        #pragma unroll
        for (int r = 0; r < 4; ++r) acc[c][r] = 0.f;

    const ushort_t* ga = A  + (size_t)(bm + srow) * K + scol;
    const ushort_t* gb = Bt + (size_t)(bn + srow) * K + scol;

    for (int k0 = 0; k0 < K; k0 += 64) {
        uint4 a0 = *(const uint4*)(ga + k0);
        uint4 a1 = *(const uint4*)(ga + k0 + 32);
        uint4 b0 = *(const uint4*)(gb + k0);
        uint4 b1 = *(const uint4*)(gb + k0 + 32);
        *(uint4*)&als[srow * 72 + scol]      = a0;
        *(uint4*)&als[srow * 72 + scol + 32] = a1;
        *(uint4*)&bls[srow * 72 + scol]      = b0;
        *(uint4*)&bls[srow * 72 + scol + 32] = b1;
        __syncthreads();
        #pragma unroll
        for (int s = 0; s < 2; ++s) {
            bf16x8 af = *(const bf16x8*)&als[(w * 16 + lr) * 72 + s * 32 + quad * 8];
            #pragma unroll
            for (int c = 0; c < 4; ++c) {
                bf16x8 bf = *(const bf16x8*)&bls[(c * 16 + lr) * 72 + s * 32 + quad * 8];
                acc[c] = __builtin_amdgcn_mfma_f32_16x16x32_bf16(af, bf, acc[c], 0, 0, 0);
            }
        }
        __syncthreads();
    }
    // epilogue: C/D layout col=lane&15, row=quad*4+reg
    #pragma unroll
    for (int c = 0; c < 4; ++c) {
        int gn = bn + c * 16 + lr;
        float bv = bias[gn];
        #pragma unroll
        for (int r = 0; r < 4; ++r) {
            int gm = bm + w * 16 + quad * 4 + r;
            float vout = acc[c][r] + bv;
            if (OUT_BF16)
                ((ushort_t*)Cout)[(size_t)gm * N + gn] = f2bf(vout);
            else
                ((float*)Cout)[(size_t)gm * N + gn] = vout;
        }
    }
}

// ---------------- staging helper: 16 bf16 -> 16 fp32 in LDS ----------------
__device__ __forceinline__ void stage16(const ushort_t* __restrict__ src, float* __restrict__ dst) {
    uint4 u0 = *(const uint4*)src;
    uint4 u1 = *(const uint4*)(src + 8);
    float4 f;
    unpack2(u0.x, f.x, f.y); unpack2(u0.y, f.z, f.w); *(float4*)(dst + 0)  = f;
    unpack2(u0.z, f.x, f.y); unpack2(u0.w, f.z, f.w); *(float4*)(dst + 4)  = f;
    unpack2(u1.x, f.x, f.y); unpack2(u1.y, f.z, f.w); *(float4*)(dst + 8)  = f;
    unpack2(u1.z, f.x, f.y); unpack2(u1.w, f.z, f.w); *(float4*)(dst + 12) = f;
}

// ---------------- fused windowed attention (one block per b, q-tile, head) ----------------
__global__ __launch_bounds__(256) void attn_kernel(
    const ushort_t* __restrict__ qkv,   // [NB*SEQ][2304] bf16
    const float* __restrict__ mmask,    // [NB][SEQ][SEQ]
    const int* __restrict__ wszp,       // [NB]
    ushort_t* __restrict__ values,      // [NB*SEQ][768] bf16
    float* __restrict__ attn_out)       // [NB][SEQ][SEQ], pre-zeroed; atomic head-mean
{
    __shared__ __align__(16) float plog[TQ][NCMAX]; // logits -> exp values
    __shared__ __align__(16) float ks[64][68];      // K/V chunk [j][d], stride 68 (16B ok, 2-way banks)
    __shared__ __align__(16) float qs[TQ][68];      // q tile
    __shared__ float invsum[TQ];
    const int tid  = threadIdx.x;
    const int iq0  = blockIdx.x * TQ;
    const int b    = blockIdx.y;
    const int h    = blockIdx.z;
    const int wsz  = wszp[b];
    const int jlo  = max(0, iq0 - wsz);
    const int jhi  = min(SEQ - 1, iq0 + TQ - 1 + wsz);
    const int ncols = jhi - jlo + 1;
    const int irow = tid >> 4;     // 0..15
    const int c16  = tid & 15;     // 0..15
    const int srow = tid >> 2;     // 0..63  (staging row)
    const int sp   = (tid & 3) * 16; // staging dim group
    const int hq   = h * 192;

    // ---- stage Q tile (bf16 -> fp32) ----
    {
        const ushort_t* src = qkv + ((size_t)(b * SEQ + iq0 + irow)) * QKVN + hq + c16 * 4;
        ushort4 u = *(const ushort4*)src;
        float4 f;
        f.x = bf2f(u.x); f.y = bf2f(u.y); f.z = bf2f(u.z); f.w = bf2f(u.w);
        *(float4*)&qs[irow][c16 * 4] = f;
    }
    __syncthreads();

    // ---- logits in 64-column chunks ----
    for (int jc0 = 0; jc0 < ncols; jc0 += 64) {
        const int nj = min(64, ncols - jc0);
        if (srow < nj)
            stage16(qkv + ((size_t)(b * SEQ + jlo + jc0 + srow)) * QKVN + hq + 64 + sp,
                    &ks[srow][sp]);
        __syncthreads();
        const int j0 = c16 * 4;
        float dot[4] = {0.f, 0.f, 0.f, 0.f};
        if (j0 < nj) {
            #pragma unroll 4
            for (int d4 = 0; d4 < 16; ++d4) {
                float4 qv = *(const float4*)&qs[irow][d4 * 4];
                #pragma unroll
                for (int c = 0; c < 4; ++c) {
                    float4 kv = *(const float4*)&ks[j0 + c][d4 * 4];
                    dot[c] = fmaf(qv.x, kv.x, dot[c]);
                    dot[c] = fmaf(qv.y, kv.y, dot[c]);
                    dot[c] = fmaf(qv.z, kv.z, dot[c]);
                    dot[c] = fmaf(qv.w, kv.w, dot[c]);
                }
            }
        }
        const int gi = iq0 + irow;
        #pragma unroll
        for (int c = 0; c < 4; ++c) {
            int j = j0 + c;
            if (j < nj) {
                int gj = jlo + jc0 + j;
                float mm = mmask[((size_t)b * SEQ + gi) * SEQ + gj];
                int dist = gi > gj ? gi - gj : gj - gi;
                plog[irow][jc0 + j] = (dist > wsz || mm == PADV) ? PADV
                                                                 : fmaf(dot[c], SCALE, mm);
            }
        }
        __syncthreads();
    }

    // ---- softmax per row (16 lanes per row, all in same wave) ----
    {
        float m = -3.4e38f;
        for (int j = c16; j < ncols; j += 16) m = fmaxf(m, plog[irow][j]);
        #pragma unroll
        for (int o = 8; o; o >>= 1) m = fmaxf(m, __shfl_xor(m, o, 16));
        float s = 0.f;
        for (int j = c16; j < ncols; j += 16) {
            float e = __expf(plog[irow][j] - m);
            plog[irow][j] = e;
            s += e;
        }
        #pragma unroll
        for (int o = 8; o; o >>= 1) s += __shfl_xor(s, o, 16);
        if (c16 == 0) invsum[irow] = 1.0f / s;
    }
    __syncthreads();

    // ---- PV with V staged through LDS ----
    float a0 = 0.f, a1 = 0.f, a2 = 0.f, a3 = 0.f;
    for (int jc0 = 0; jc0 < ncols; jc0 += 64) {
        const int nj = min(64, ncols - jc0);
        if (srow < nj)
            stage16(qkv + ((size_t)(b * SEQ + jlo + jc0 + srow)) * QKVN + hq + 128 + sp,
                    &ks[srow][sp]);
        __syncthreads();
        #pragma unroll 4
        for (int j = 0; j < nj; ++j) {
            float p = plog[irow][jc0 + j];
            float4 v = *(const float4*)&ks[j][c16 * 4];
            a0 = fmaf(p, v.x, a0);
            a1 = fmaf(p, v.y, a1);
            a2 = fmaf(p, v.z, a2);
            a3 = fmaf(p, v.w, a3);
        }
        __syncthreads();
    }
    {
        float is = invsum[irow];
        ushort4 st;
        st.x = f2bf(a0 * is); st.y = f2bf(a1 * is);
        st.z = f2bf(a2 * is); st.w = f2bf(a3 * is);
        *(ushort4*)(values + ((size_t)(b * SEQ + iq0 + irow)) * EDIM + h * 64 + c16 * 4) = st;
    }

    // ---- head-mean contribution via atomics (attn_out pre-zeroed) ----
    {
        const float invH = 1.0f / (float)NH;
        float* ab = attn_out + ((size_t)b * SEQ + iq0) * SEQ + jlo;
        for (int r = 0; r < TQ; ++r) {
            float sc = invsum[r] * invH;
            for (int j = tid; j < ncols; j += 256)
                atomicAdd(&ab[(size_t)r * SEQ + j], plog[r][j] * sc);
        }
    }
}

extern "C" void kernel_launch(void* const* d_in, const int* in_sizes, int n_in,
                              void* d_out, int out_size, void* d_ws, size_t ws_size,
                              hipStream_t stream) {
    const float* x      = (const float*)d_in[0];
    const int*   pad    = (const int*)d_in[1];
    const float* mmask  = (const float*)d_in[2];
    const float* qkv_w  = (const float*)d_in[3];
    const float* qkv_b  = (const float*)d_in[4];
    const float* o_w    = (const float*)d_in[5];
    const float* o_b    = (const float*)d_in[6];

    float* out_o    = (float*)d_out;
    float* out_attn = out_o + (size_t)NB * SEQ * EDIM;

    // workspace layout (bytes total ~55 MB; round-1 used 63 MB so ws_size suffices)
    ushort_t* qkv    = (ushort_t*)d_ws;                         // NB*SEQ*2304 bf16
    ushort_t* xb     = qkv + (size_t)NB * SEQ * QKVN;           // x as bf16 (aliased w/ values)
    ushort_t* values = xb;                                      // written after xb consumed
    ushort_t* wqkvb  = xb + (size_t)NB * SEQ * DIN;             // qkv_w bf16
    ushort_t* wob    = wqkvb + (size_t)QKVN * DIN;              // o_w bf16
    int*      wszp   = (int*)(wob + (size_t)EDIM * EDIM);

    // zero attn_mean output (out-of-window must be exactly 0; atomics accumulate into it)
    hipMemsetAsync(out_attn, 0, (size_t)NB * SEQ * SEQ * sizeof(float), stream);

    wsz_kernel<<<NB, 256, 0, stream>>>(pad, wszp);

    const int nx = NB * SEQ * DIN / 4, nw1 = QKVN * DIN / 4, nw2 = EDIM * EDIM / 4;
    cvt_kernel<<<(nx  + 255) / 256, 256, 0, stream>>>(x,     xb,    nx);
    cvt_kernel<<<(nw1 + 255) / 256, 256, 0, stream>>>(qkv_w, wqkvb, nw1);
    cvt_kernel<<<(nw2 + 255) / 256, 256, 0, stream>>>(o_w,   wob,   nw2);

    // qkv = x @ qkv_w^T + qkv_b  (bf16 MFMA, bf16 out)
    mfma_gemm_kernel<1><<<dim3(QKVN / 64, (NB * SEQ) / 64), 256, 0, stream>>>(
        xb, wqkvb, qkv_b, (void*)qkv, NB * SEQ, QKVN, DIN);

    // fused windowed attention, head-parallel
    attn_kernel<<<dim3(SEQ / TQ, NB, NH), 256, 0, stream>>>(
        qkv, mmask, wszp, values, out_attn);

    // o = values @ o_w^T + o_b  (bf16 MFMA, fp32 out)
    mfma_gemm_kernel<0><<<dim3(EDIM / 64, (NB * SEQ) / 64), 256, 0, stream>>>(
        values, wob, o_b, (void*)out_o, NB * SEQ, EDIM, EDIM);
}

// Round 3
// 461.589 us; speedup vs baseline: 4.5034x; 1.6916x over previous
//
#include <hip/hip_runtime.h>

#define SEQ 2048
#define NB 4
#define DIN 768
#define EDIM 768
#define NH 12
#define QKVN 2304
#define QKW 1536
#define SCALE 0.125f
#define PADV -1e9f
#define INV12 (0.0833333333f)

typedef unsigned short ushort_t;
typedef __attribute__((ext_vector_type(8))) short bf16x8;
typedef __attribute__((ext_vector_type(4))) float f32x4;

__device__ __forceinline__ float bf2f(ushort_t u) {
    union { unsigned int i; float f; } v; v.i = ((unsigned int)u) << 16; return v.f;
}
__device__ __forceinline__ ushort_t f2bf(float f) {
    union { float f; unsigned int i; } v; v.f = f;
    unsigned int r = (v.i + 0x7fffu + ((v.i >> 16) & 1u)) >> 16;
    return (ushort_t)r;
}
__device__ __forceinline__ void gl_lds16(const ushort_t* g, ushort_t* l) {
    __builtin_amdgcn_global_load_lds(
        (const __attribute__((address_space(1))) unsigned int*)(g),
        (__attribute__((address_space(3))) unsigned int*)(l),
        16, 0, 0);
}

// ---------------- per-batch window size ----------------
__global__ void wsz_kernel(const int* __restrict__ mask, int* __restrict__ wszp) {
    int b = blockIdx.x;
    __shared__ int cnt;
    if (threadIdx.x == 0) cnt = 0;
    __syncthreads();
    int local = 0;
    for (int s = threadIdx.x; s < SEQ; s += blockDim.x)
        local += (mask[b * SEQ + s] == 0) ? 1 : 0;
    for (int o = 32; o; o >>= 1) local += __shfl_down(local, o, 64);
    if ((threadIdx.x & 63) == 0) atomicAdd(&cnt, local);
    __syncthreads();
    if (threadIdx.x == 0) {
        int len = cnt; if (len > 2048) len = 2048;
        float w = ceilf(((float)len * 10.0f) / 100.0f);
        int wsz = (int)w;
        if (wsz < 2) wsz = 2;
        wszp[b] = wsz;
    }
}

// ---------------- fp32 -> bf16 conversion ----------------
__global__ void cvt_kernel(const float* __restrict__ in, ushort_t* __restrict__ out, int n4) {
    int i = blockIdx.x * blockDim.x + threadIdx.x;
    if (i < n4) {
        float4 f = ((const float4*)in)[i];
        ushort4 u;
        u.x = f2bf(f.x); u.y = f2bf(f.y); u.z = f2bf(f.z); u.w = f2bf(f.w);
        ((ushort4*)out)[i] = u;
    }
}

// ---------------- mmask nonzero-tile flags ----------------
// flags[b][i16][jt] = 1 if any mmask != 0 in tile (16 rows x 64 cols)
__global__ void flag_kernel(const float* __restrict__ mmask, const int* __restrict__ wszp,
                            int* __restrict__ flags) {
    const int b = blockIdx.z, i16 = blockIdx.y;
    const int wsz = wszp[b];
    const int i0 = i16 * 16;
    const int jt0 = max(0, i0 - wsz) >> 6;
    const int jt1 = min(SEQ - 1, i0 + 15 + wsz) >> 6;
    const int jt = jt0 + blockIdx.x;
    if (jt > jt1) return;
    int any = 0;
    for (int e = threadIdx.x; e < 1024; e += 256) {
        int row = e >> 6, col = e & 63;
        float v = mmask[((size_t)b * SEQ + i0 + row) * SEQ + jt * 64 + col];
        any |= (v != 0.f);
    }
    if (any) flags[(b * 128 + i16) * 32 + jt] = 1;
}

// ---------------- 128x128 bf16 MFMA GEMM (m97-style, global_load_lds + swizzle) ----------
// C[M][N] = A[M][K] @ Bw[N][K]^T + bias
// MODE 0: fp32 out.  MODE 1: bf16 out split into qk (cols%192<128) and vt (transposed V).
template<int MODE>
__global__ __launch_bounds__(256) void mfma_gemm128(
    const ushort_t* __restrict__ A, const ushort_t* __restrict__ Bw,
    const float* __restrict__ bias, float* __restrict__ outf,
    ushort_t* __restrict__ qk, ushort_t* __restrict__ vt, int N, int K)
{
    __shared__ __align__(16) ushort_t Al[128 * 64];
    __shared__ __align__(16) ushort_t Bl[128 * 64];
    const int tid  = threadIdx.x;
    const int w    = tid >> 6;
    const int l    = tid & 63;
    const int quad = l >> 4;
    const int lr   = l & 15;
    const int mw   = (w >> 1) * 64;
    const int nw   = (w & 1) * 64;
    const int bm   = blockIdx.y * 128;
    const int bn   = blockIdx.x * 128;
    const int srow = l >> 3;                 // 0..7
    const int sg   = (l & 7) ^ srow;         // swizzled col-group

    f32x4 acc[4][4];
    #pragma unroll
    for (int i = 0; i < 4; ++i)
        #pragma unroll
        for (int j = 0; j < 4; ++j)
            #pragma unroll
            for (int r = 0; r < 4; ++r) acc[i][j][r] = 0.f;

    const ushort_t* ga = A  + (size_t)(bm + w * 32 + srow) * K + sg * 8;
    const ushort_t* gb = Bw + (size_t)(bn + w * 32 + srow) * K + sg * 8;
    ushort_t* la = &Al[(w * 32) * 64];
    ushort_t* lb = &Bl[(w * 32) * 64];

    for (int k0 = 0; k0 < K; k0 += 64) {
        __syncthreads();
        #pragma unroll
        for (int i = 0; i < 4; ++i)
            gl_lds16(ga + (size_t)(i * 8) * K + k0, la + i * 8 * 64);
        #pragma unroll
        for (int i = 0; i < 4; ++i)
            gl_lds16(gb + (size_t)(i * 8) * K + k0, lb + i * 8 * 64);
        __syncthreads();
        #pragma unroll
        for (int s = 0; s < 2; ++s) {
            bf16x8 af[4], bf[4];
            #pragma unroll
            for (int t = 0; t < 4; ++t)
                af[t] = *(const bf16x8*)&Al[(mw + t * 16 + lr) * 64 + (((4 * s + quad) ^ (lr & 7)) * 8)];
            #pragma unroll
            for (int t = 0; t < 4; ++t)
                bf[t] = *(const bf16x8*)&Bl[(nw + t * 16 + lr) * 64 + (((4 * s + quad) ^ (lr & 7)) * 8)];
            #pragma unroll
            for (int mt = 0; mt < 4; ++mt)
                #pragma unroll
                for (int nt = 0; nt < 4; ++nt)
                    acc[mt][nt] = __builtin_amdgcn_mfma_f32_16x16x32_bf16(af[mt], bf[nt], acc[mt][nt], 0, 0, 0);
        }
    }

    #pragma unroll
    for (int nt = 0; nt < 4; ++nt) {
        const int gn = bn + nw + nt * 16 + lr;
        const float bv = bias[gn];
        const int hh  = gn / 192;
        const int rem = gn - hh * 192;
        #pragma unroll
        for (int mt = 0; mt < 4; ++mt) {
            #pragma unroll
            for (int r = 0; r < 4; ++r) {
                const int gm = bm + mw + mt * 16 + quad * 4 + r;
                const float v = acc[mt][nt][r] + bv;
                if (MODE == 0) {
                    outf[(size_t)gm * N + gn] = v;
                } else {
                    const ushort_t bfv = f2bf(v);
                    if (rem < 128) {
                        qk[(size_t)gm * QKW + hh * 128 + rem] = bfv;
                    } else {
                        const int bb  = gm >> 11;
                        const int tok = gm & (SEQ - 1);
                        vt[((size_t)(bb * NH + hh) * 64 + (rem - 128)) * SEQ + tok] = bfv;
                    }
                }
            }
        }
    }
}

// ---------------- fused windowed attention, MFMA, barrier-free ----------------
// grid (SEQ/64, NB, NH), 256 thr = 4 waves; wave w -> q rows [bx*64+w*16, +16)
__global__ __launch_bounds__(256) void attn_kernel(
    const ushort_t* __restrict__ qk,    // [NB*SEQ][1536] bf16 (Q|K per head)
    const ushort_t* __restrict__ vt,    // [NB*NH*64][SEQ] bf16 (V transposed)
    const float* __restrict__ mmask,    // [NB][SEQ][SEQ]
    const int* __restrict__ wszp,       // [NB]
    const int* __restrict__ flags,      // [NB][128][32]
    ushort_t* __restrict__ values,      // [NB*SEQ][768] bf16
    float* __restrict__ attn_out)       // [NB][SEQ][SEQ], pre-zeroed
{
    __shared__ __align__(16) ushort_t Pb[4][16][72];
    const int tid  = threadIdx.x;
    const int w    = tid >> 6;
    const int lane = tid & 63;
    const int quad = lane >> 4;
    const int lr   = lane & 15;
    const int b    = blockIdx.y;
    const int h    = blockIdx.z;
    const int iq0  = blockIdx.x * 64 + w * 16;
    const int wsz  = wszp[b];
    const int jt0  = max(0, iq0 - wsz) >> 6;
    const int jt1  = min(SEQ - 1, iq0 + 15 + wsz) >> 6;
    const int nch  = jt1 - jt0 + 1;
    const int fbase = (b * 128 + (iq0 >> 4)) * 32;

    // Q A-fragments (row = iq0+lr, k = s*32 + quad*8)
    const ushort_t* qbase = qk + (size_t)(b * SEQ + iq0 + lr) * QKW + h * 128;
    bf16x8 qf0 = *(const bf16x8*)(qbase + quad * 8);
    bf16x8 qf1 = *(const bf16x8*)(qbase + 32 + quad * 8);

    const ushort_t* kbase = qk + (size_t)b * SEQ * QKW + h * 128 + 64;
    const ushort_t* vbase = vt + (size_t)(b * NH + h) * 64 * SEQ;

    // ---------------- pass A: row sums ----------------
    float lsum[4] = {0.f, 0.f, 0.f, 0.f};
    for (int ci = 0; ci < nch; ++ci) {
        const int jt = jt0 + ci;
        const int jc = jt << 6;
        bf16x8 kf[4][2];
        #pragma unroll
        for (int t = 0; t < 4; ++t) {
            const ushort_t* kr = kbase + (size_t)(jc + t * 16 + lr) * QKW;
            kf[t][0] = *(const bf16x8*)(kr + quad * 8);
            kf[t][1] = *(const bf16x8*)(kr + 32 + quad * 8);
        }
        f32x4 s4[4];
        #pragma unroll
        for (int t = 0; t < 4; ++t) {
            #pragma unroll
            for (int r = 0; r < 4; ++r) s4[t][r] = 0.f;
            s4[t] = __builtin_amdgcn_mfma_f32_16x16x32_bf16(qf0, kf[t][0], s4[t], 0, 0, 0);
            s4[t] = __builtin_amdgcn_mfma_f32_16x16x32_bf16(qf1, kf[t][1], s4[t], 0, 0, 0);
        }
        const int anym = flags[fbase + jt];
        #pragma unroll
        for (int t = 0; t < 4; ++t) {
            const int gj = jc + t * 16 + lr;
            #pragma unroll
            for (int r = 0; r < 4; ++r) {
                const int gi = iq0 + quad * 4 + r;
                float mm = 0.f;
                if (anym) mm = mmask[((size_t)b * SEQ + gi) * SEQ + gj];
                const int dist = gi > gj ? gi - gj : gj - gi;
                const bool dead = (dist > wsz) || (mm == PADV);
                const float p = dead ? 0.f : __expf(fmaf(s4[t][r], SCALE, mm));
                lsum[r] += p;
            }
        }
    }
    #pragma unroll
    for (int r = 0; r < 4; ++r) {
        #pragma unroll
        for (int m = 8; m; m >>= 1) lsum[r] += __shfl_xor(lsum[r], m, 16);
    }
    float invl[4], invl12[4];
    #pragma unroll
    for (int r = 0; r < 4; ++r) { invl[r] = 1.0f / lsum[r]; invl12[r] = invl[r] * INV12; }

    // ---------------- pass B: P, attn atomics, PV ----------------
    f32x4 oacc[4];
    #pragma unroll
    for (int t = 0; t < 4; ++t)
        #pragma unroll
        for (int r = 0; r < 4; ++r) oacc[t][r] = 0.f;

    for (int ci = 0; ci < nch; ++ci) {
        const int jt = jt0 + ci;
        const int jc = jt << 6;
        bf16x8 kf[4][2];
        #pragma unroll
        for (int t = 0; t < 4; ++t) {
            const ushort_t* kr = kbase + (size_t)(jc + t * 16 + lr) * QKW;
            kf[t][0] = *(const bf16x8*)(kr + quad * 8);
            kf[t][1] = *(const bf16x8*)(kr + 32 + quad * 8);
        }
        f32x4 s4[4];
        #pragma unroll
        for (int t = 0; t < 4; ++t) {
            #pragma unroll
            for (int r = 0; r < 4; ++r) s4[t][r] = 0.f;
            s4[t] = __builtin_amdgcn_mfma_f32_16x16x32_bf16(qf0, kf[t][0], s4[t], 0, 0, 0);
            s4[t] = __builtin_amdgcn_mfma_f32_16x16x32_bf16(qf1, kf[t][1], s4[t], 0, 0, 0);
        }
        const int anym = flags[fbase + jt];
        #pragma unroll
        for (int t = 0; t < 4; ++t) {
            const int gj = jc + t * 16 + lr;
            #pragma unroll
            for (int r = 0; r < 4; ++r) {
                const int gi = iq0 + quad * 4 + r;
                float mm = 0.f;
                if (anym) mm = mmask[((size_t)b * SEQ + gi) * SEQ + gj];
                const int dist = gi > gj ? gi - gj : gj - gi;
                const bool dead = (dist > wsz) || (mm == PADV);
                const float p = dead ? 0.f : __expf(fmaf(s4[t][r], SCALE, mm));
                Pb[w][quad * 4 + r][t * 16 + lr] = f2bf(p);
                const float av = p * invl12[r];
                if (av != 0.f)
                    atomicAdd(&attn_out[((size_t)b * SEQ + gi) * SEQ + gj], av);
            }
        }
        // PV: A = P (LDS, this wave's rows), B = vt rows (global)
        bf16x8 pa0 = *(const bf16x8*)&Pb[w][lr][quad * 8];
        bf16x8 pa1 = *(const bf16x8*)&Pb[w][lr][32 + quad * 8];
        #pragma unroll
        for (int t = 0; t < 4; ++t) {
            const ushort_t* vr = vbase + (size_t)(t * 16 + lr) * SEQ + jc;
            bf16x8 vf0 = *(const bf16x8*)(vr + quad * 8);
            bf16x8 vf1 = *(const bf16x8*)(vr + 32 + quad * 8);
            oacc[t] = __builtin_amdgcn_mfma_f32_16x16x32_bf16(pa0, vf0, oacc[t], 0, 0, 0);
            oacc[t] = __builtin_amdgcn_mfma_f32_16x16x32_bf16(pa1, vf1, oacc[t], 0, 0, 0);
        }
    }

    // epilogue: values (bf16)
    #pragma unroll
    for (int t = 0; t < 4; ++t) {
        #pragma unroll
        for (int r = 0; r < 4; ++r) {
            const int row = iq0 + quad * 4 + r;
            values[(size_t)(b * SEQ + row) * EDIM + h * 64 + t * 16 + lr] =
                f2bf(oacc[t][r] * invl[r]);
        }
    }
}

extern "C" void kernel_launch(void* const* d_in, const int* in_sizes, int n_in,
                              void* d_out, int out_size, void* d_ws, size_t ws_size,
                              hipStream_t stream) {
    const float* x      = (const float*)d_in[0];
    const int*   pad    = (const int*)d_in[1];
    const float* mmask  = (const float*)d_in[2];
    const float* qkv_w  = (const float*)d_in[3];
    const float* qkv_b  = (const float*)d_in[4];
    const float* o_w    = (const float*)d_in[5];
    const float* o_b    = (const float*)d_in[6];

    float* out_o    = (float*)d_out;
    float* out_attn = out_o + (size_t)NB * SEQ * EDIM;

    // workspace layout (~55.2 MB total)
    ushort_t* qk     = (ushort_t*)d_ws;                       // NB*SEQ*1536 (Q|K)   25.2 MB
    ushort_t* vt     = qk + (size_t)NB * SEQ * QKW;           // NB*NH*64*SEQ        12.6 MB
    ushort_t* xb     = vt + (size_t)NB * NH * 64 * SEQ;       // x bf16              12.6 MB
    ushort_t* values = xb;                                    // alias (after GEMM1)
    ushort_t* wqkvb  = xb + (size_t)NB * SEQ * DIN;           // qkv_w bf16           3.5 MB
    ushort_t* wob    = wqkvb + (size_t)QKVN * DIN;            // o_w bf16             1.2 MB
    int*      wszp   = (int*)(wob + (size_t)EDIM * EDIM);
    int*      flags  = wszp + 4;                              // NB*128*32 ints      64 KB

    hipMemsetAsync(out_attn, 0, (size_t)NB * SEQ * SEQ * sizeof(float), stream);
    hipMemsetAsync(flags, 0, (size_t)NB * 128 * 32 * sizeof(int), stream);

    wsz_kernel<<<NB, 256, 0, stream>>>(pad, wszp);
    flag_kernel<<<dim3(8, 128, NB), 256, 0, stream>>>(mmask, wszp, flags);

    const int nx = NB * SEQ * DIN / 4, nw1 = QKVN * DIN / 4, nw2 = EDIM * EDIM / 4;
    cvt_kernel<<<(nx  + 255) / 256, 256, 0, stream>>>(x,     xb,    nx);
    cvt_kernel<<<(nw1 + 255) / 256, 256, 0, stream>>>(qkv_w, wqkvb, nw1);
    cvt_kernel<<<(nw2 + 255) / 256, 256, 0, stream>>>(o_w,   wob,   nw2);

    // qkv = x @ qkv_w^T + qkv_b -> qk buffer + transposed V
    mfma_gemm128<1><<<dim3(QKVN / 128, (NB * SEQ) / 128), 256, 0, stream>>>(
        xb, wqkvb, qkv_b, nullptr, qk, vt, QKVN, DIN);

    // fused windowed attention
    attn_kernel<<<dim3(SEQ / 64, NB, NH), 256, 0, stream>>>(
        qk, vt, mmask, wszp, flags, values, out_attn);

    // o = values @ o_w^T + o_b
    mfma_gemm128<0><<<dim3(EDIM / 128, (NB * SEQ) / 128), 256, 0, stream>>>(
        values, wob, o_b, out_o, nullptr, nullptr, EDIM, EDIM);
}